// Round 4
// baseline (2696.818 us; speedup 1.0000x reference)
//
#include <hip/hip_runtime.h>
#include <hip/hip_bf16.h>

// Team-of-2 LSTM, sentinel-handshake exchange (no flags, no acquire/release).
// 256 blocks x 512 threads; block i pairs with i^128. Each block holds half
// of W_hh (512 gate rows x 256 K, bf16) in the unified VGPR/AGPR file.
// Per step, h halves are exchanged through d_ws via relaxed agent-scope
// 8B packets; readers poll their own packet until != SENTINEL (tanh-bounded
// bf16 data can never be 0xFFFF...), then restore the sentinel.
// Needs ws_size >= 2 MB.

#define TT 256
#define HH 256
#define BC 16
#define SENT 0xFFFFFFFFFFFFFFFFULL

typedef __attribute__((ext_vector_type(8))) short short8;
typedef __attribute__((ext_vector_type(4))) float floatx4;
typedef unsigned long long ull;

__device__ __forceinline__ unsigned short f2bf(float f) {
    union { float f; unsigned u; } v; v.f = f;
    unsigned r = v.u + 0x7FFFu + ((v.u >> 16) & 1u);   // RNE, finite inputs only
    return (unsigned short)(r >> 16);
}
__device__ __forceinline__ float sigf(float x) {
    return __builtin_amdgcn_rcpf(1.f + __expf(-x));
}
__device__ __forceinline__ float tanh_(float x) {
    return 1.f - 2.f * __builtin_amdgcn_rcpf(__expf(2.f * x) + 1.f);
}

__global__ __attribute__((amdgpu_flat_work_group_size(512, 512),
                          amdgpu_waves_per_eu(2, 2)))
void lstm_team2(
    const float* __restrict__ y_hist, const float* __restrict__ h0,
    const float* __restrict__ c0, const float* __restrict__ W_ih,
    const float* __restrict__ W_hh, const float* __restrict__ b_ih,
    const float* __restrict__ b_hh, const float* __restrict__ W_fc,
    const float* __restrict__ b_fc, float* __restrict__ out,
    char* __restrict__ hx)
{
    // h state: [batch 16][hidden 256] bf16, row stride 512B, XOR-swizzled
    __shared__ __align__(16) unsigned short hbuf[2][BC * 256];  // 16 KB
    __shared__ float xbuf[TT * BC];                             // 16 KB
    __shared__ float outacc[BC * 2];

    const int tid = threadIdx.x;
    const int w   = tid >> 6;          // wave 0..7
    const int l   = tid & 63;
    const int lr  = l & 15;            // batch lane (B col / C col)
    const int lg  = l >> 4;            // group 0..3
    const int bid = blockIdx.x;
    const int rho = bid >> 7;          // role 0/1: hidden half
    const int pid = bid ^ 128;         // partner block
    const int b0  = (bid & 127) * BC;  // team batch base
    const int hbase = rho * 128;       // this block's hidden half
    const int u   = hbase + 16 * w + 4 * lg;  // lane's hidden base (4 units)

    // ---- stage x: [t][batch] fp32 ----
    for (int idx = tid; idx < TT * BC; idx += 512) {
        int bb = idx >> 8, t = idx & 255;
        xbuf[t * BC + bb] = y_hist[(size_t)(b0 + bb) * TT + t];
    }
    // ---- stage h0 (full 256 hidden) -> bf16 swizzled LDS buf0 ----
    {
        char* hb = (char*)&hbuf[0][0];
        for (int idx = tid; idx < BC * 128; idx += 512) {
            int bb = idx >> 7, d = idx & 127;
            const float* hp = &h0[(size_t)(b0 + bb) * HH + 2 * d];
            unsigned val = (unsigned)f2bf(hp[0]) | ((unsigned)f2bf(hp[1]) << 16);
            *(unsigned*)(hb + bb * 512 + ((d * 4) ^ ((bb & 7) << 4))) = val;
        }
    }
    if (tid < BC * 2) outacc[tid] = 0.f;

    // ---- per-lane constants ----
    float cc[4];
#pragma unroll
    for (int r = 0; r < 4; ++r)
        cc[r] = c0[(size_t)(b0 + lr) * HH + u + r];

    float wxv[16], biasv[16];
#pragma unroll
    for (int g = 0; g < 4; ++g)
#pragma unroll
        for (int r = 0; r < 4; ++r) {
            int gc = g * 256 + u + r;
            wxv[g * 4 + r]   = W_ih[gc];
            biasv[g * 4 + r] = b_ih[gc] + b_hh[gc];
        }

    // ---- W half -> register-resident bf16 A-fragments ----
    short8 wfrag[32];
    {
        const int wrow = hbase + 16 * w + lr;
        const int cb = 8 * lg;
#pragma unroll
        for (int g = 0; g < 4; ++g)
#pragma unroll
            for (int s = 0; s < 8; ++s) {
                const float* p = &W_hh[(size_t)(g * 256 + wrow) * HH + cb + 32 * s];
                short8 f;
#pragma unroll
                for (int i = 0; i < 8; ++i) f[i] = (short)f2bf(p[i]);
                wfrag[g * 8 + s] = f;
            }
    }
#pragma unroll
    for (int i = 0; i < 32; ++i)
        asm volatile("" : "+v"(wfrag[i]));

    __syncthreads();

    const unsigned sw = (unsigned)((lr & 7) << 4);
    const unsigned rdbase = (unsigned)(lr * 512);
    const unsigned phcol = (unsigned)((1 - rho) * 256);  // partner half byte col
    const unsigned cw = (unsigned)(2 * u);               // own half byte col
    const int sOwn = 4 * rho;                            // own k-range s base
    const int sPar = 4 * (1 - rho);                      // partner k-range s base
    float hv[4] = {0.f, 0.f, 0.f, 0.f};

#pragma unroll 1
    for (int t = 0; t < TT; ++t) {
        char* rb = (char*)&hbuf[t & 1][0];
        char* wb = (char*)&hbuf[(t + 1) & 1][0];

        float xv = xbuf[t * BC + lr];
        floatx4 acc[4];
#pragma unroll
        for (int g = 0; g < 4; ++g)
#pragma unroll
            for (int r = 0; r < 4; ++r)
                acc[g][r] = fmaf(xv, wxv[g * 4 + r], biasv[g * 4 + r]);

        // ---- own-half MFMAs (data local since last barrier) ----
#pragma unroll
        for (int si = 0; si < 4; ++si) {
            int s = sOwn + si;
            short8 bfr = *(const short8*)(rb + rdbase +
                             (((unsigned)(16 * lg + 64 * s)) ^ sw));
#pragma unroll
            for (int g = 0; g < 4; ++g)
                acc[g] = __builtin_amdgcn_mfma_f32_16x16x32_bf16(
                             wfrag[g * 8 + s], bfr, acc[g], 0, 0, 0);
        }

        // ---- partner half: per-lane sentinel poll (= the data load) ----
        if (t > 0) {
            ull* slot = (ull*)(hx + ((size_t)(pid * 2 + (t & 1))) * 4096);
            ull v;
            do {
                v = __hip_atomic_load(slot + tid, __ATOMIC_RELAXED,
                                      __HIP_MEMORY_SCOPE_AGENT);
            } while (v == SENT);
            int bb = tid >> 5;
            unsigned c = phcol + 8u * (tid & 31);
            *(ull*)(rb + bb * 512 + (c ^ ((unsigned)(bb & 7) << 4))) = v;
            __hip_atomic_store(slot + tid, SENT, __ATOMIC_RELAXED,
                               __HIP_MEMORY_SCOPE_AGENT);
            __syncthreads();   // vmcnt-drains the sentinel store, publishes LDS
        }

        // ---- partner-half MFMAs ----
#pragma unroll
        for (int si = 0; si < 4; ++si) {
            int s = sPar + si;
            short8 bfr = *(const short8*)(rb + rdbase +
                             (((unsigned)(16 * lg + 64 * s)) ^ sw));
#pragma unroll
            for (int g = 0; g < 4; ++g)
                acc[g] = __builtin_amdgcn_mfma_f32_16x16x32_bf16(
                             wfrag[g * 8 + s], bfr, acc[g], 0, 0, 0);
        }

        // ---- gates -> c,h ----
#pragma unroll
        for (int r = 0; r < 4; ++r) {
            float iv = sigf(acc[0][r]);
            float fv = sigf(acc[1][r]);
            float gv = tanh_(acc[2][r]);
            float ov = sigf(acc[3][r]);
            float c2 = fmaf(fv, cc[r], iv * gv);
            cc[r] = c2;
            hv[r] = ov * tanh_(c2);
        }
        unsigned lo = (unsigned)f2bf(hv[0]) | ((unsigned)f2bf(hv[1]) << 16);
        unsigned hi = (unsigned)f2bf(hv[2]) | ((unsigned)f2bf(hv[3]) << 16);
        ull pkv = (ull)lo | ((ull)hi << 32);

        // own half -> partner (issue ASAP; partner polls these very words)
        ull* gdst = (ull*)(hx + ((size_t)(bid * 2 + ((t + 1) & 1))) * 4096
                              + lr * 256 + 32 * w + 8 * lg);
        __hip_atomic_store(gdst, pkv, __ATOMIC_RELAXED,
                           __HIP_MEMORY_SCOPE_AGENT);
        // own half -> next LDS buffer
        *(ull*)(wb + rdbase + (cw ^ sw)) = pkv;

        __syncthreads();
    }

    // ---- epilogue: partial out = h_T(half) @ W_fc^T, teams combine ----
    float wfcv[8];
#pragma unroll
    for (int o = 0; o < 2; ++o)
#pragma unroll
        for (int r = 0; r < 4; ++r)
            wfcv[o * 4 + r] = W_fc[o * HH + u + r];

    float p0 = hv[0]*wfcv[0] + hv[1]*wfcv[1] + hv[2]*wfcv[2] + hv[3]*wfcv[3];
    float p1 = hv[0]*wfcv[4] + hv[1]*wfcv[5] + hv[2]*wfcv[6] + hv[3]*wfcv[7];
    p0 += __shfl_xor(p0, 16, 64); p0 += __shfl_xor(p0, 32, 64);
    p1 += __shfl_xor(p1, 16, 64); p1 += __shfl_xor(p1, 32, 64);
    if (lg == 0) {
        atomicAdd(&outacc[lr * 2 + 0], p0);
        atomicAdd(&outacc[lr * 2 + 1], p1);
    }
    __syncthreads();
    if (tid < BC * 2) {
        int bb = tid >> 1, o = tid & 1;
        float v = outacc[tid] + (rho == 0 ? b_fc[o] : 0.f);
        atomicAdd(&out[(size_t)(b0 + bb) * 2 + o], v);
    }
}

extern "C" void kernel_launch(void* const* d_in, const int* in_sizes, int n_in,
                              void* d_out, int out_size, void* d_ws, size_t ws_size,
                              hipStream_t stream) {
    const float* y_hist = (const float*)d_in[0];
    const float* h0     = (const float*)d_in[1];
    const float* c0     = (const float*)d_in[2];
    const float* W_ih   = (const float*)d_in[3];
    const float* W_hh   = (const float*)d_in[4];
    const float* b_ih   = (const float*)d_in[5];
    const float* b_hh   = (const float*)d_in[6];
    const float* W_fc   = (const float*)d_in[7];
    const float* b_fc   = (const float*)d_in[8];

    char* hx = (char*)d_ws;   // 256 blocks x 2 parities x 4 KB = 2 MB

    // Graph-safe per-launch init: sentinel-fill exchange buffers, zero out.
    hipMemsetAsync(d_out, 0, (size_t)out_size * sizeof(float), stream);
    hipMemsetAsync(hx, 0xFF, 256 * 2 * 4096, stream);

    lstm_team2<<<256, 512, 0, stream>>>(
        y_hist, h0, c0, W_ih, W_hh, b_ih, b_hh, W_fc, b_fc,
        (float*)d_out, hx);
}